// Round 12
// baseline (579.423 us; speedup 1.0000x reference)
//
#include <hip/hip_runtime.h>

#define Nn 40000
#define Ee 600000
#define Hh 128
#define Gg 32
#define Cc 6
#define NB 157                   // ceil(Nn/256) scan blocks
#define PCAP (Ee + 4 * Nn + 8)   // padded colidx capacity (760008, mult of 4, +8 slack for prologue reads)
#define LSTR 136                 // LDS A-tile row stride (u16)

typedef __bf16 bf16x8 __attribute__((ext_vector_type(8)));
typedef float floatx4 __attribute__((ext_vector_type(4)));
typedef unsigned short u16;
typedef unsigned int u32;

__device__ __forceinline__ float b2f(u32 u) {
    union { u32 i; float f; } v; v.i = u << 16; return v.f;
}
__device__ __forceinline__ float b2f_hi(u32 u) {
    union { u32 i; float f; } v; v.i = u & 0xffff0000u; return v.f;
}
__device__ __forceinline__ u16 f2b(float f) {
    union { float f; u32 i; } v; v.f = f;
    u32 r = v.i + 0x7fffu + ((v.i >> 16) & 1u);   // RNE
    return (u16)(r >> 16);
}
__device__ __forceinline__ u32 pack2(float a, float b) {
    return (u32)f2b(a) | ((u32)f2b(b) << 16);
}

// ---------------- setup: zero counts/emb/gcnt, fill padded colidx with dummy Nn, zero pad rows ----------------
__global__ __launch_bounds__(256) void k_setup(int* counts, float* emb, int* gcnt, int* pcol,
                                               u16* xb, u16* hA, u16* hB, float* dinv) {
    int i = blockIdx.x * 256 + threadIdx.x;
    if (i < Nn) counts[i] = 0;
    if (i < Gg * Hh) emb[i] = 0.f;
    if (i < Gg) gcnt[i] = 0;
    if (i * 4 < PCAP) {                      // PCAP multiple of 4
        int4 v = { Nn, Nn, Nn, Nn };
        *(int4*)(pcol + i * 4) = v;
    }
    if (blockIdx.x == 0) {
        int t = threadIdx.x;
        uint4 z = { 0, 0, 0, 0 };
        if (t < 16)              *(uint4*)(xb + (size_t)Nn * 128 + t * 8) = z;
        else if (t < 32)         *(uint4*)(hA + (size_t)Nn * 128 + (t - 16) * 8) = z;
        else if (t < 48)         *(uint4*)(hB + (size_t)Nn * 128 + (t - 32) * 8) = z;
        else if (t == 48)        dinv[Nn] = 0.f;
    }
}

// ---------------- degree count + per-graph node count ----------------
__global__ __launch_bounds__(256) void k_count(const int* __restrict__ dst, const int* __restrict__ batch,
                                               int* __restrict__ counts, int* __restrict__ gcnt) {
    int i = blockIdx.x * 256 + threadIdx.x;
    if (i < Ee) atomicAdd(&counts[dst[i]], 1);
    if (i < Nn) atomicAdd(&gcnt[batch[i]], 1);
}

// ---------------- 3-phase multi-block exclusive scan over pad-to-4 counts ----------------
__global__ __launch_bounds__(256) void k_scan1(const int* __restrict__ counts, int* __restrict__ bsum) {
    __shared__ int sm[256];
    int t = threadIdx.x;
    int i = blockIdx.x * 256 + t;
    sm[t] = (i < Nn) ? ((counts[i] + 3) & ~3) : 0;
    __syncthreads();
    for (int ofs = 128; ofs > 0; ofs >>= 1) {
        if (t < ofs) sm[t] += sm[t + ofs];
        __syncthreads();
    }
    if (t == 0) bsum[blockIdx.x] = sm[0];
}

__global__ __launch_bounds__(256) void k_scan2(const int* __restrict__ bsum, int* __restrict__ boff,
                                               int* __restrict__ row_ptr) {
    __shared__ int sm[256];
    int t = threadIdx.x;
    int v = (t < NB) ? bsum[t] : 0;
    sm[t] = v;
    __syncthreads();
    for (int ofs = 1; ofs < 256; ofs <<= 1) {
        int u = (t >= ofs) ? sm[t - ofs] : 0;
        __syncthreads();
        sm[t] += u;
        __syncthreads();
    }
    if (t < NB) boff[t] = sm[t] - v;
    if (t == 255) row_ptr[Nn] = sm[255];
}

// cursor may alias counts — each thread reads counts[i] before writing cursor[i].
__global__ __launch_bounds__(256) void k_scan3(const int* counts, const int* __restrict__ boff,
                                               int* row_ptr, int* cursor, float* dinv) {
    __shared__ int sm[256];
    int t = threadIdx.x;
    int i = blockIdx.x * 256 + t;
    int c = (i < Nn) ? counts[i] : 0;
    int pc = (c + 3) & ~3;
    sm[t] = pc;
    __syncthreads();
    for (int ofs = 1; ofs < 256; ofs <<= 1) {
        int u = (t >= ofs) ? sm[t - ofs] : 0;
        __syncthreads();
        sm[t] += u;
        __syncthreads();
    }
    if (i < Nn) {
        int excl = sm[t] - pc + boff[blockIdx.x];
        row_ptr[i] = excl;
        cursor[i] = excl;
        dinv[i] = rsqrtf((float)(c + 1));
    }
}

__global__ __launch_bounds__(256) void k_scatter(const int* __restrict__ src, const int* __restrict__ dst,
                                                 int* __restrict__ cursor, int* __restrict__ colidx) {
    int i = blockIdx.x * 256 + threadIdx.x;
    if (i < Ee) {
        int d = dst[i];
        int p = atomicAdd(&cursor[d], 1);
        if ((u32)p < (u32)PCAP) colidx[p] = src[i];
    }
}

// ---------------- fused cast (f32->bf16 rows) + weight pack (MFMA B-frag order) ----------------
__global__ __launch_bounds__(256) void k_castpack(const float* __restrict__ x, u16* __restrict__ xb,
                                                  const float* w0, const float* w1, const float* w2,
                                                  const float* w3, const float* w4, const float* w5,
                                                  const float* w6, u16* __restrict__ pwdst) {
    if (blockIdx.x < 448) {
        int idx = blockIdx.x * 256 + threadIdx.x;
        if (idx < 7 * 16384) {
            const float* ws[7] = { w0, w1, w2, w3, w4, w5, w6 };
            int mat = idx >> 14, r = idx & 16383;
            int j = r & 7, n = (r >> 3) & 15, q = (r >> 7) & 3, nt = (r >> 9) & 7, t = r >> 12;
            pwdst[idx] = f2b(ws[mat][(t * 32 + q * 8 + j) * 128 + nt * 16 + n]);
        }
    } else {
        int i = ((blockIdx.x - 448) * 256 + threadIdx.x) * 4;   // covers Nn*128 = 5.12M exactly (5000 blocks)
        float4 v = *(const float4*)(x + i);
        ushort4 o = { f2b(v.x), f2b(v.y), f2b(v.z), f2b(v.w) };
        *(ushort4*)(xb + i) = o;
    }
}

// ---------------- FUSED layer: wave-uniform gather-agg -> LDS -> 16-row MFMA GEMM [-> pooled epilogue] ----------------
// GraphConv (gcn=0): hout = relu(hin@Bself + agg(hin)@Bagg + b)
// GCNConv   (gcn=1): hout = [relu]( [di*sum ds*hin_s + di^2*hin_i]@Bagg + b )
// Block = 16 nodes / 4 waves; wave processes its 4 nodes SEQUENTIALLY (node is wave-uniform ->
// scalar loop bounds, no exec-mask divergence). Gather: 4 edges x 16 lanes x 16 B per instruction.
// Padded CSR (trips multiple of 4; pad edges hit zero row Nn, dinv[Nn]=0).
#define UNPACK_ADD(V)                                   \
    a0 += b2f((V).x);  a1 += b2f_hi((V).x);             \
    a2 += b2f((V).y);  a3 += b2f_hi((V).y);             \
    a4 += b2f((V).z);  a5 += b2f_hi((V).z);             \
    a6 += b2f((V).w);  a7 += b2f_hi((V).w);

#define UNPACK_FMA(V, d)                                      \
    a0 += (d) * b2f((V).x);  a1 += (d) * b2f_hi((V).x);       \
    a2 += (d) * b2f((V).y);  a3 += (d) * b2f_hi((V).y);       \
    a4 += (d) * b2f((V).z);  a5 += (d) * b2f_hi((V).z);       \
    a6 += (d) * b2f((V).w);  a7 += (d) * b2f_hi((V).w);

#define FOLD(v) v += __shfl_xor(v, 16); v += __shfl_xor(v, 32);

__global__ __launch_bounds__(256) void k_layer(const u16* __restrict__ hin,
                                               const u16* __restrict__ Bp_agg,
                                               const u16* __restrict__ Bp_self,
                                               const float* __restrict__ bias,
                                               u16* __restrict__ hout,
                                               const int* __restrict__ prow,
                                               const int* __restrict__ pcol,
                                               const float* __restrict__ dinv,
                                               const int* __restrict__ batch,
                                               float* __restrict__ emb,
                                               int gcn, int relu, int dopool) {
    __shared__ u16 Asm[16 * LSTR];
    __shared__ float Psm[16][132];   // +4 pad: 2-way-max bank aliasing on epilogue writes
    int wave = threadIdx.x >> 6, lane = threadIdx.x & 63;
    int m0 = blockIdx.x * 16;
    int es = lane >> 4, l = lane & 15;

    // ---- phase A: aggregate 4 nodes sequentially (wave-uniform bounds) ----
    {
        const u16* base = hin + l * 8;
        for (int k = 0; k < 4; ++k) {
            int nloc = wave * 4 + k;
            int node = m0 + nloc;
            int beg = prow[node], end = prow[node + 1];
            float a0 = 0.f, a1 = 0.f, a2 = 0.f, a3 = 0.f, a4 = 0.f, a5 = 0.f, a6 = 0.f, a7 = 0.f;
            int sc = pcol[beg + es];                      // stray-safe (PCAP slack)
            if (gcn) {
                for (int e = beg; e < end; e += 4) {
                    int sn = pcol[e + 4 + es];            // next quad (value unused if loop exits)
                    float d = dinv[sc];
                    uint4 v = *(const uint4*)(base + (size_t)sc * 128);
                    UNPACK_FMA(v, d)
                    sc = sn;
                }
            } else {
                for (int e = beg; e < end; e += 4) {
                    int sn = pcol[e + 4 + es];
                    uint4 v = *(const uint4*)(base + (size_t)sc * 128);
                    UNPACK_ADD(v)
                    sc = sn;
                }
            }
            FOLD(a0) FOLD(a1) FOLD(a2) FOLD(a3) FOLD(a4) FOLD(a5) FOLD(a6) FOLD(a7)
            if (gcn) {
                float di = dinv[node], d2n = di * di;
                uint4 us = *(const uint4*)(base + (size_t)node * 128);
                a0 = di * a0 + d2n * b2f(us.x);  a1 = di * a1 + d2n * b2f_hi(us.x);
                a2 = di * a2 + d2n * b2f(us.y);  a3 = di * a3 + d2n * b2f_hi(us.y);
                a4 = di * a4 + d2n * b2f(us.z);  a5 = di * a5 + d2n * b2f_hi(us.z);
                a6 = di * a6 + d2n * b2f(us.w);  a7 = di * a7 + d2n * b2f_hi(us.w);
            }
            if (es == 0) {
                uint4 o = { pack2(a0, a1), pack2(a2, a3), pack2(a4, a5), pack2(a6, a7) };
                *(uint4*)&Asm[nloc * LSTR + l * 8] = o;
            }
        }
    }
    __syncthreads();

    // ---- phase B: 16-row GEMM; wave handles cols [wave*32, wave*32+32) ----
    {
        int n = lane & 15, q = lane >> 4;
        floatx4 acc0 = (floatx4){0.f, 0.f, 0.f, 0.f};
        floatx4 acc1 = (floatx4){0.f, 0.f, 0.f, 0.f};
        int nt0 = wave * 2, nt1 = wave * 2 + 1;
#pragma unroll
        for (int t = 0; t < 4; t++) {
            bf16x8 a = *(const bf16x8*)&Asm[n * LSTR + q * 8 + t * 32];
            const u16* bp = Bp_agg + t * 4096 + q * 128 + n * 8;
            bf16x8 b0 = *(const bf16x8*)(bp + nt0 * 512);
            bf16x8 b1 = *(const bf16x8*)(bp + nt1 * 512);
            acc0 = __builtin_amdgcn_mfma_f32_16x16x32_bf16(a, b0, acc0, 0, 0, 0);
            acc1 = __builtin_amdgcn_mfma_f32_16x16x32_bf16(a, b1, acc1, 0, 0, 0);
        }
        if (!gcn) {
            const u16* arow = hin + (size_t)(m0 + n) * 128 + q * 8;
#pragma unroll
            for (int t = 0; t < 4; t++) {
                bf16x8 a = *(const bf16x8*)(arow + t * 32);
                const u16* bp = Bp_self + t * 4096 + q * 128 + n * 8;
                bf16x8 b0 = *(const bf16x8*)(bp + nt0 * 512);
                bf16x8 b1 = *(const bf16x8*)(bp + nt1 * 512);
                acc0 = __builtin_amdgcn_mfma_f32_16x16x32_bf16(a, b0, acc0, 0, 0, 0);
                acc1 = __builtin_amdgcn_mfma_f32_16x16x32_bf16(a, b1, acc1, 0, 0, 0);
            }
        }
        // D: row = q*4 + r, col = nt*16 + n
        if (dopool) {
            // L5: stash f32 results in LDS, then block-segmented pool into emb (batch sorted)
#pragma unroll
            for (int j = 0; j < 2; j++) {
                int col = (wave * 2 + j) * 16 + n;
                float bv = bias[col];
                floatx4 ac = j ? acc1 : acc0;
#pragma unroll
                for (int r = 0; r < 4; r++)
                    Psm[q * 4 + r][col] = ac[r] + bv;
            }
            __syncthreads();
            if (threadIdx.x < 128) {
                int col = threadIdx.x;
                int g0 = batch[m0], g1 = batch[m0 + 15];
                for (int g = g0; g <= g1; ++g) {
                    float s = 0.f;
#pragma unroll
                    for (int i = 0; i < 16; ++i)
                        if (batch[m0 + i] == g) s += Psm[i][col];
                    atomicAdd(&emb[g * 128 + col], s);
                }
            }
        } else {
#pragma unroll
            for (int j = 0; j < 2; j++) {
                int col = (wave * 2 + j) * 16 + n;
                float bv = bias[col];
                floatx4 ac = j ? acc1 : acc0;
#pragma unroll
                for (int r = 0; r < 4; r++) {
                    float v = ac[r] + bv;
                    if (relu) v = fmaxf(v, 0.f);
                    hout[(size_t)(m0 + q * 4 + r) * 128 + col] = f2b(v);
                }
            }
        }
    }
}

// ---------------- final: embedding + logits (f32 out) ----------------
__global__ __launch_bounds__(256) void k_final(const float* __restrict__ emb, const int* __restrict__ gcnt,
                                               const float* __restrict__ lw, const float* __restrict__ lb,
                                               float* __restrict__ out) {
    int t = threadIdx.x;
    for (int i = t; i < Gg * Hh; i += 256) {
        int g = i >> 7;
        float c = fmaxf((float)gcnt[g], 1.f);
        out[Gg * Cc + i] = emb[i] / c;
    }
    if (t < Gg * Cc) {
        int g = t / Cc, c = t % Cc;
        float cn = fmaxf((float)gcnt[g], 1.f);
        float s = lb[c];
        for (int f = 0; f < Hh; f++)
            s += (emb[g * 128 + f] / cn) * lw[f * Cc + c];
        out[t] = s;
    }
}

extern "C" void kernel_launch(void* const* d_in, const int* in_sizes, int n_in,
                              void* d_out, int out_size, void* d_ws, size_t ws_size,
                              hipStream_t stream) {
    const float* x       = (const float*)d_in[0];
    const int*   ei      = (const int*)d_in[1];
    const int*   batch   = (const int*)d_in[2];
    const float* w1_root = (const float*)d_in[3];
    const float* w1_rel  = (const float*)d_in[4];
    const float* b1      = (const float*)d_in[5];
    const float* w2_root = (const float*)d_in[6];
    const float* w2_rel  = (const float*)d_in[7];
    const float* b2      = (const float*)d_in[8];
    const float* w3      = (const float*)d_in[9];
    const float* b3      = (const float*)d_in[10];
    const float* w4      = (const float*)d_in[11];
    const float* b4      = (const float*)d_in[12];
    const float* w5      = (const float*)d_in[13];
    const float* b5      = (const float*)d_in[14];
    const float* lw      = (const float*)d_in[15];
    const float* lb      = (const float*)d_in[16];
    const int* srcp = ei;
    const int* dstp = ei + Ee;
    float* out = (float*)d_out;

    char* w = (char*)d_ws;
    size_t off = 0;
    auto alloc = [&](size_t bytes) { size_t r = off; off += (bytes + 255) & ~(size_t)255; return r; };
    int*   counts  = (int*)(w + alloc(Nn * 4));              // doubles as scatter cursor
    int*   row_ptr = (int*)(w + alloc((Nn + 1) * 4));        // padded offsets
    int*   colidx  = (int*)(w + alloc((size_t)PCAP * 4));    // padded colidx (+slack)
    float* dinv    = (float*)(w + alloc((Nn + 1) * 4));      // +1: dinv[Nn]=0 for pad edges
    float* emb     = (float*)(w + alloc(Gg * Hh * 4));
    int*   gcnt    = (int*)(w + alloc(Gg * 4));
    int*   bsum    = (int*)(w + alloc(NB * 4));
    int*   boff    = (int*)(w + alloc(256 * 4));
    u16*   pw      = (u16*)(w + alloc(7 * 16384 * 2));
    u16*   xb      = (u16*)(w + alloc((size_t)(Nn + 1) * Hh * 2));  // +1 zero row
    u16*   hA      = (u16*)(w + alloc((size_t)(Nn + 1) * Hh * 2));  // +1 zero row
    u16*   hB      = (u16*)(w + alloc((size_t)(Nn + 1) * Hh * 2));  // +1 zero row
    (void)ws_size;

    u16* pw1r = pw + 0 * 16384;
    u16* pw1l = pw + 1 * 16384;
    u16* pw2r = pw + 2 * 16384;
    u16* pw2l = pw + 3 * 16384;
    u16* pw3  = pw + 4 * 16384;
    u16* pw4  = pw + 5 * 16384;
    u16* pw5  = pw + 6 * 16384;
    const u16* nil = (const u16*)nullptr;

    // CSR build (pad-to-4) + cast/pack
    hipLaunchKernelGGL(k_setup, dim3((PCAP / 4 + 255) / 256), dim3(256), 0, stream,
                       counts, emb, gcnt, colidx, xb, hA, hB, dinv);
    hipLaunchKernelGGL(k_count, dim3((Ee + 255) / 256), dim3(256), 0, stream, dstp, batch, counts, gcnt);
    hipLaunchKernelGGL(k_scan1, dim3(NB), dim3(256), 0, stream, counts, bsum);
    hipLaunchKernelGGL(k_scan2, dim3(1), dim3(256), 0, stream, bsum, boff, row_ptr);
    hipLaunchKernelGGL(k_scan3, dim3(NB), dim3(256), 0, stream, counts, boff, row_ptr, counts, dinv);
    hipLaunchKernelGGL(k_scatter, dim3((Ee + 255) / 256), dim3(256), 0, stream, srcp, dstp, counts, colidx);
    hipLaunchKernelGGL(k_castpack, dim3(448 + Nn * Hh / 1024), dim3(256), 0, stream,
                       x, xb, w1_root, w1_rel, w2_root, w2_rel, w3, w4, w5, pw);

    // fused layers (block = 16 nodes, 2500 blocks)
    hipLaunchKernelGGL(k_layer, dim3(Nn / 16), dim3(256), 0, stream,
                       xb, pw1l, pw1r, b1, hA, row_ptr, colidx, dinv, batch, emb, 0, 1, 0);
    hipLaunchKernelGGL(k_layer, dim3(Nn / 16), dim3(256), 0, stream,
                       hA, pw2l, pw2r, b2, hB, row_ptr, colidx, dinv, batch, emb, 0, 1, 0);
    hipLaunchKernelGGL(k_layer, dim3(Nn / 16), dim3(256), 0, stream,
                       hB, pw3, nil, b3, hA, row_ptr, colidx, dinv, batch, emb, 1, 1, 0);
    hipLaunchKernelGGL(k_layer, dim3(Nn / 16), dim3(256), 0, stream,
                       hA, pw4, nil, b4, hB, row_ptr, colidx, dinv, batch, emb, 1, 1, 0);
    // L5 GCN, no relu, pooled epilogue (no hout write)
    hipLaunchKernelGGL(k_layer, dim3(Nn / 16), dim3(256), 0, stream,
                       hB, pw5, nil, b5, hA, row_ptr, colidx, dinv, batch, emb, 1, 0, 1);

    // final linear + embedding output
    hipLaunchKernelGGL(k_final, dim3(1), dim3(256), 0, stream, emb, gcnt, lw, lb, out);
}

// Round 13
// 348.604 us; speedup vs baseline: 1.6621x; 1.6621x over previous
//
#include <hip/hip_runtime.h>

#define Nn 40000
#define Ee 600000
#define Hh 128
#define Gg 32
#define Cc 6
#define NB 157                   // ceil(Nn/256) scan blocks
#define PCAP (Ee + 4 * Nn + 8)   // padded colidx capacity (760008, mult of 4, +8 slack for prologue reads)
#define LSTR 136                 // LDS A-tile row stride (u16)

typedef __bf16 bf16x8 __attribute__((ext_vector_type(8)));
typedef float floatx4 __attribute__((ext_vector_type(4)));
typedef unsigned short u16;
typedef unsigned int u32;

__device__ __forceinline__ float b2f(u32 u) {
    union { u32 i; float f; } v; v.i = u << 16; return v.f;
}
__device__ __forceinline__ float b2f_hi(u32 u) {
    union { u32 i; float f; } v; v.i = u & 0xffff0000u; return v.f;
}
__device__ __forceinline__ u16 f2b(float f) {
    union { float f; u32 i; } v; v.f = f;
    u32 r = v.i + 0x7fffu + ((v.i >> 16) & 1u);   // RNE
    return (u16)(r >> 16);
}
__device__ __forceinline__ u32 pack2(float a, float b) {
    return (u32)f2b(a) | ((u32)f2b(b) << 16);
}

// ---------------- setup: zero counts/emb, fill padded colidx with dummy Nn, zero pad rows ----------------
__global__ __launch_bounds__(256) void k_setup(int* counts, float* emb, int* pcol,
                                               u16* xb, u16* hA, u16* hB, float* dinv) {
    int i = blockIdx.x * 256 + threadIdx.x;
    if (i < Nn) counts[i] = 0;
    if (i < Gg * Hh) emb[i] = 0.f;
    if (i * 4 < PCAP) {                      // PCAP multiple of 4
        int4 v = { Nn, Nn, Nn, Nn };
        *(int4*)(pcol + i * 4) = v;
    }
    if (blockIdx.x == 0) {
        int t = threadIdx.x;
        uint4 z = { 0, 0, 0, 0 };
        if (t < 16)              *(uint4*)(xb + (size_t)Nn * 128 + t * 8) = z;
        else if (t < 32)         *(uint4*)(hA + (size_t)Nn * 128 + (t - 16) * 8) = z;
        else if (t < 48)         *(uint4*)(hB + (size_t)Nn * 128 + (t - 32) * 8) = z;
        else if (t == 48)        dinv[Nn] = 0.f;
    }
}

// ---------------- degree count (edge atomics over 40k counters — low contention) ----------------
// NOTE (R12 post-mortem): do NOT fold per-graph node counting in here — 40k atomics onto 32
// addresses serialize ~1250-deep and cost ~260 µs. gcnt is derived by binary search in k_final.
__global__ __launch_bounds__(256) void k_count(const int* __restrict__ dst, int* __restrict__ counts) {
    int i = blockIdx.x * 256 + threadIdx.x;
    if (i < Ee) atomicAdd(&counts[dst[i]], 1);
}

// ---------------- 3-phase multi-block exclusive scan over pad-to-4 counts ----------------
__global__ __launch_bounds__(256) void k_scan1(const int* __restrict__ counts, int* __restrict__ bsum) {
    __shared__ int sm[256];
    int t = threadIdx.x;
    int i = blockIdx.x * 256 + t;
    sm[t] = (i < Nn) ? ((counts[i] + 3) & ~3) : 0;
    __syncthreads();
    for (int ofs = 128; ofs > 0; ofs >>= 1) {
        if (t < ofs) sm[t] += sm[t + ofs];
        __syncthreads();
    }
    if (t == 0) bsum[blockIdx.x] = sm[0];
}

__global__ __launch_bounds__(256) void k_scan2(const int* __restrict__ bsum, int* __restrict__ boff,
                                               int* __restrict__ row_ptr) {
    __shared__ int sm[256];
    int t = threadIdx.x;
    int v = (t < NB) ? bsum[t] : 0;
    sm[t] = v;
    __syncthreads();
    for (int ofs = 1; ofs < 256; ofs <<= 1) {
        int u = (t >= ofs) ? sm[t - ofs] : 0;
        __syncthreads();
        sm[t] += u;
        __syncthreads();
    }
    if (t < NB) boff[t] = sm[t] - v;
    if (t == 255) row_ptr[Nn] = sm[255];
}

// cursor may alias counts — each thread reads counts[i] before writing cursor[i].
__global__ __launch_bounds__(256) void k_scan3(const int* counts, const int* __restrict__ boff,
                                               int* row_ptr, int* cursor, float* dinv) {
    __shared__ int sm[256];
    int t = threadIdx.x;
    int i = blockIdx.x * 256 + t;
    int c = (i < Nn) ? counts[i] : 0;
    int pc = (c + 3) & ~3;
    sm[t] = pc;
    __syncthreads();
    for (int ofs = 1; ofs < 256; ofs <<= 1) {
        int u = (t >= ofs) ? sm[t - ofs] : 0;
        __syncthreads();
        sm[t] += u;
        __syncthreads();
    }
    if (i < Nn) {
        int excl = sm[t] - pc + boff[blockIdx.x];
        row_ptr[i] = excl;
        cursor[i] = excl;
        dinv[i] = rsqrtf((float)(c + 1));
    }
}

__global__ __launch_bounds__(256) void k_scatter(const int* __restrict__ src, const int* __restrict__ dst,
                                                 int* __restrict__ cursor, int* __restrict__ colidx) {
    int i = blockIdx.x * 256 + threadIdx.x;
    if (i < Ee) {
        int d = dst[i];
        int p = atomicAdd(&cursor[d], 1);
        if ((u32)p < (u32)PCAP) colidx[p] = src[i];
    }
}

// ---------------- fused cast (f32->bf16 rows) + weight pack (MFMA B-frag order) ----------------
__global__ __launch_bounds__(256) void k_castpack(const float* __restrict__ x, u16* __restrict__ xb,
                                                  const float* w0, const float* w1, const float* w2,
                                                  const float* w3, const float* w4, const float* w5,
                                                  const float* w6, u16* __restrict__ pwdst) {
    if (blockIdx.x < 448) {
        int idx = blockIdx.x * 256 + threadIdx.x;
        if (idx < 7 * 16384) {
            const float* ws[7] = { w0, w1, w2, w3, w4, w5, w6 };
            int mat = idx >> 14, r = idx & 16383;
            int j = r & 7, n = (r >> 3) & 15, q = (r >> 7) & 3, nt = (r >> 9) & 7, t = r >> 12;
            pwdst[idx] = f2b(ws[mat][(t * 32 + q * 8 + j) * 128 + nt * 16 + n]);
        }
    } else {
        int i = ((blockIdx.x - 448) * 256 + threadIdx.x) * 4;   // covers Nn*128 = 5.12M exactly
        float4 v = *(const float4*)(x + i);
        ushort4 o = { f2b(v.x), f2b(v.y), f2b(v.z), f2b(v.w) };
        *(ushort4*)(xb + i) = o;
    }
}

// ---------------- FUSED layer: wave-uniform gather-agg -> LDS -> 16-row MFMA GEMM [-> pooled epilogue] ----------------
#define UNPACK_ADD(V)                                   \
    a0 += b2f((V).x);  a1 += b2f_hi((V).x);             \
    a2 += b2f((V).y);  a3 += b2f_hi((V).y);             \
    a4 += b2f((V).z);  a5 += b2f_hi((V).z);             \
    a6 += b2f((V).w);  a7 += b2f_hi((V).w);

#define UNPACK_FMA(V, d)                                      \
    a0 += (d) * b2f((V).x);  a1 += (d) * b2f_hi((V).x);       \
    a2 += (d) * b2f((V).y);  a3 += (d) * b2f_hi((V).y);       \
    a4 += (d) * b2f((V).z);  a5 += (d) * b2f_hi((V).z);       \
    a6 += (d) * b2f((V).w);  a7 += (d) * b2f_hi((V).w);

#define FOLD(v) v += __shfl_xor(v, 16); v += __shfl_xor(v, 32);

__global__ __launch_bounds__(256) void k_layer(const u16* __restrict__ hin,
                                               const u16* __restrict__ Bp_agg,
                                               const u16* __restrict__ Bp_self,
                                               const float* __restrict__ bias,
                                               u16* __restrict__ hout,
                                               const int* __restrict__ prow,
                                               const int* __restrict__ pcol,
                                               const float* __restrict__ dinv,
                                               const int* __restrict__ batch,
                                               float* __restrict__ emb,
                                               int gcn, int relu, int dopool) {
    __shared__ u16 Asm[16 * LSTR];
    __shared__ float Psm[16][132];   // +4 pad: 2-way-max bank aliasing on epilogue writes
    int wave = threadIdx.x >> 6, lane = threadIdx.x & 63;
    int m0 = blockIdx.x * 16;
    int es = lane >> 4, l = lane & 15;

    // ---- phase A: aggregate 4 nodes sequentially (wave-uniform bounds) ----
    {
        const u16* base = hin + l * 8;
        for (int k = 0; k < 4; ++k) {
            int nloc = wave * 4 + k;
            int node = m0 + nloc;
            int beg = prow[node], end = prow[node + 1];
            float a0 = 0.f, a1 = 0.f, a2 = 0.f, a3 = 0.f, a4 = 0.f, a5 = 0.f, a6 = 0.f, a7 = 0.f;
            int sc = pcol[beg + es];                      // stray-safe (PCAP slack)
            if (gcn) {
                for (int e = beg; e < end; e += 4) {
                    int sn = pcol[e + 4 + es];            // next quad (value unused if loop exits)
                    float d = dinv[sc];
                    uint4 v = *(const uint4*)(base + (size_t)sc * 128);
                    UNPACK_FMA(v, d)
                    sc = sn;
                }
            } else {
                for (int e = beg; e < end; e += 4) {
                    int sn = pcol[e + 4 + es];
                    uint4 v = *(const uint4*)(base + (size_t)sc * 128);
                    UNPACK_ADD(v)
                    sc = sn;
                }
            }
            FOLD(a0) FOLD(a1) FOLD(a2) FOLD(a3) FOLD(a4) FOLD(a5) FOLD(a6) FOLD(a7)
            if (gcn) {
                float di = dinv[node], d2n = di * di;
                uint4 us = *(const uint4*)(base + (size_t)node * 128);
                a0 = di * a0 + d2n * b2f(us.x);  a1 = di * a1 + d2n * b2f_hi(us.x);
                a2 = di * a2 + d2n * b2f(us.y);  a3 = di * a3 + d2n * b2f_hi(us.y);
                a4 = di * a4 + d2n * b2f(us.z);  a5 = di * a5 + d2n * b2f_hi(us.z);
                a6 = di * a6 + d2n * b2f(us.w);  a7 = di * a7 + d2n * b2f_hi(us.w);
            }
            if (es == 0) {
                uint4 o = { pack2(a0, a1), pack2(a2, a3), pack2(a4, a5), pack2(a6, a7) };
                *(uint4*)&Asm[nloc * LSTR + l * 8] = o;
            }
        }
    }
    __syncthreads();

    // ---- phase B: 16-row GEMM; wave handles cols [wave*32, wave*32+32) ----
    {
        int n = lane & 15, q = lane >> 4;
        floatx4 acc0 = (floatx4){0.f, 0.f, 0.f, 0.f};
        floatx4 acc1 = (floatx4){0.f, 0.f, 0.f, 0.f};
        int nt0 = wave * 2, nt1 = wave * 2 + 1;
#pragma unroll
        for (int t = 0; t < 4; t++) {
            bf16x8 a = *(const bf16x8*)&Asm[n * LSTR + q * 8 + t * 32];
            const u16* bp = Bp_agg + t * 4096 + q * 128 + n * 8;
            bf16x8 b0 = *(const bf16x8*)(bp + nt0 * 512);
            bf16x8 b1 = *(const bf16x8*)(bp + nt1 * 512);
            acc0 = __builtin_amdgcn_mfma_f32_16x16x32_bf16(a, b0, acc0, 0, 0, 0);
            acc1 = __builtin_amdgcn_mfma_f32_16x16x32_bf16(a, b1, acc1, 0, 0, 0);
        }
        if (!gcn) {
            const u16* arow = hin + (size_t)(m0 + n) * 128 + q * 8;
#pragma unroll
            for (int t = 0; t < 4; t++) {
                bf16x8 a = *(const bf16x8*)(arow + t * 32);
                const u16* bp = Bp_self + t * 4096 + q * 128 + n * 8;
                bf16x8 b0 = *(const bf16x8*)(bp + nt0 * 512);
                bf16x8 b1 = *(const bf16x8*)(bp + nt1 * 512);
                acc0 = __builtin_amdgcn_mfma_f32_16x16x32_bf16(a, b0, acc0, 0, 0, 0);
                acc1 = __builtin_amdgcn_mfma_f32_16x16x32_bf16(a, b1, acc1, 0, 0, 0);
            }
        }
        // D: row = q*4 + r, col = nt*16 + n
        if (dopool) {
#pragma unroll
            for (int j = 0; j < 2; j++) {
                int col = (wave * 2 + j) * 16 + n;
                float bv = bias[col];
                floatx4 ac = j ? acc1 : acc0;
#pragma unroll
                for (int r = 0; r < 4; r++)
                    Psm[q * 4 + r][col] = ac[r] + bv;
            }
            __syncthreads();
            if (threadIdx.x < 128) {
                int col = threadIdx.x;
                int g0 = batch[m0], g1 = batch[m0 + 15];
                for (int g = g0; g <= g1; ++g) {
                    float s = 0.f;
#pragma unroll
                    for (int i = 0; i < 16; ++i)
                        if (batch[m0 + i] == g) s += Psm[i][col];
                    atomicAdd(&emb[g * 128 + col], s);
                }
            }
        } else {
#pragma unroll
            for (int j = 0; j < 2; j++) {
                int col = (wave * 2 + j) * 16 + n;
                float bv = bias[col];
                floatx4 ac = j ? acc1 : acc0;
#pragma unroll
                for (int r = 0; r < 4; r++) {
                    float v = ac[r] + bv;
                    if (relu) v = fmaxf(v, 0.f);
                    hout[(size_t)(m0 + q * 4 + r) * 128 + col] = f2b(v);
                }
            }
        }
    }
}

// ---------------- final: gcnt via binary search (batch sorted) + embedding + logits (f32 out) ----------------
__global__ __launch_bounds__(256) void k_final(const float* __restrict__ emb, const int* __restrict__ batch,
                                               const float* __restrict__ lw, const float* __restrict__ lb,
                                               float* __restrict__ out) {
    __shared__ float cnt[Gg];
    int t = threadIdx.x;
    if (t < Gg) {
        int lo = 0, hi = Nn;
        while (lo < hi) { int m = (lo + hi) >> 1; if (batch[m] < t) lo = m + 1; else hi = m; }
        int lb0 = lo;
        lo = 0; hi = Nn;
        int tg = t + 1;
        while (lo < hi) { int m = (lo + hi) >> 1; if (batch[m] < tg) lo = m + 1; else hi = m; }
        cnt[t] = fmaxf((float)(lo - lb0), 1.f);
    }
    __syncthreads();
    for (int i = t; i < Gg * Hh; i += 256) {
        int g = i >> 7;
        out[Gg * Cc + i] = emb[i] / cnt[g];
    }
    if (t < Gg * Cc) {
        int g = t / Cc, c = t % Cc;
        float cn = cnt[g];
        float s = lb[c];
        for (int f = 0; f < Hh; f++)
            s += (emb[g * 128 + f] / cn) * lw[f * Cc + c];
        out[t] = s;
    }
}

extern "C" void kernel_launch(void* const* d_in, const int* in_sizes, int n_in,
                              void* d_out, int out_size, void* d_ws, size_t ws_size,
                              hipStream_t stream) {
    const float* x       = (const float*)d_in[0];
    const int*   ei      = (const int*)d_in[1];
    const int*   batch   = (const int*)d_in[2];
    const float* w1_root = (const float*)d_in[3];
    const float* w1_rel  = (const float*)d_in[4];
    const float* b1      = (const float*)d_in[5];
    const float* w2_root = (const float*)d_in[6];
    const float* w2_rel  = (const float*)d_in[7];
    const float* b2      = (const float*)d_in[8];
    const float* w3      = (const float*)d_in[9];
    const float* b3      = (const float*)d_in[10];
    const float* w4      = (const float*)d_in[11];
    const float* b4      = (const float*)d_in[12];
    const float* w5      = (const float*)d_in[13];
    const float* b5      = (const float*)d_in[14];
    const float* lw      = (const float*)d_in[15];
    const float* lb      = (const float*)d_in[16];
    const int* srcp = ei;
    const int* dstp = ei + Ee;
    float* out = (float*)d_out;

    char* w = (char*)d_ws;
    size_t off = 0;
    auto alloc = [&](size_t bytes) { size_t r = off; off += (bytes + 255) & ~(size_t)255; return r; };
    int*   counts  = (int*)(w + alloc(Nn * 4));              // doubles as scatter cursor
    int*   row_ptr = (int*)(w + alloc((Nn + 1) * 4));        // padded offsets
    int*   colidx  = (int*)(w + alloc((size_t)PCAP * 4));    // padded colidx (+slack)
    float* dinv    = (float*)(w + alloc((Nn + 1) * 4));      // +1: dinv[Nn]=0 for pad edges
    float* emb     = (float*)(w + alloc(Gg * Hh * 4));
    int*   bsum    = (int*)(w + alloc(NB * 4));
    int*   boff    = (int*)(w + alloc(256 * 4));
    u16*   pw      = (u16*)(w + alloc(7 * 16384 * 2));
    u16*   xb      = (u16*)(w + alloc((size_t)(Nn + 1) * Hh * 2));  // +1 zero row
    u16*   hA      = (u16*)(w + alloc((size_t)(Nn + 1) * Hh * 2));  // +1 zero row
    u16*   hB      = (u16*)(w + alloc((size_t)(Nn + 1) * Hh * 2));  // +1 zero row
    (void)ws_size;

    u16* pw1r = pw + 0 * 16384;
    u16* pw1l = pw + 1 * 16384;
    u16* pw2r = pw + 2 * 16384;
    u16* pw2l = pw + 3 * 16384;
    u16* pw3  = pw + 4 * 16384;
    u16* pw4  = pw + 5 * 16384;
    u16* pw5  = pw + 6 * 16384;
    const u16* nil = (const u16*)nullptr;

    // CSR build (pad-to-4) + cast/pack
    hipLaunchKernelGGL(k_setup, dim3((PCAP / 4 + 255) / 256), dim3(256), 0, stream,
                       counts, emb, colidx, xb, hA, hB, dinv);
    hipLaunchKernelGGL(k_count, dim3((Ee + 255) / 256), dim3(256), 0, stream, dstp, counts);
    hipLaunchKernelGGL(k_scan1, dim3(NB), dim3(256), 0, stream, counts, bsum);
    hipLaunchKernelGGL(k_scan2, dim3(1), dim3(256), 0, stream, bsum, boff, row_ptr);
    hipLaunchKernelGGL(k_scan3, dim3(NB), dim3(256), 0, stream, counts, boff, row_ptr, counts, dinv);
    hipLaunchKernelGGL(k_scatter, dim3((Ee + 255) / 256), dim3(256), 0, stream, srcp, dstp, counts, colidx);
    hipLaunchKernelGGL(k_castpack, dim3(448 + Nn * Hh / 1024), dim3(256), 0, stream,
                       x, xb, w1_root, w1_rel, w2_root, w2_rel, w3, w4, w5, pw);

    // fused layers (block = 16 nodes, 2500 blocks)
    hipLaunchKernelGGL(k_layer, dim3(Nn / 16), dim3(256), 0, stream,
                       xb, pw1l, pw1r, b1, hA, row_ptr, colidx, dinv, batch, emb, 0, 1, 0);
    hipLaunchKernelGGL(k_layer, dim3(Nn / 16), dim3(256), 0, stream,
                       hA, pw2l, pw2r, b2, hB, row_ptr, colidx, dinv, batch, emb, 0, 1, 0);
    hipLaunchKernelGGL(k_layer, dim3(Nn / 16), dim3(256), 0, stream,
                       hB, pw3, nil, b3, hA, row_ptr, colidx, dinv, batch, emb, 1, 1, 0);
    hipLaunchKernelGGL(k_layer, dim3(Nn / 16), dim3(256), 0, stream,
                       hA, pw4, nil, b4, hB, row_ptr, colidx, dinv, batch, emb, 1, 1, 0);
    // L5 GCN, no relu, pooled epilogue (no hout write)
    hipLaunchKernelGGL(k_layer, dim3(Nn / 16), dim3(256), 0, stream,
                       hB, pw5, nil, b5, hA, row_ptr, colidx, dinv, batch, emb, 1, 0, 1);

    // final linear + embedding output (gcnt derived in-kernel by binary search)
    hipLaunchKernelGGL(k_final, dim3(1), dim3(256), 0, stream, emb, batch, lw, lb, out);
}

// Round 14
// 319.400 us; speedup vs baseline: 1.8141x; 1.0914x over previous
//
#include <hip/hip_runtime.h>

#define Nn 40000
#define Ee 600000
#define Hh 128
#define Gg 32
#define Cc 6
#define NB 157                   // ceil(Nn/256) scan blocks
#define PCAP (Ee + 8 * Nn + 8)   // padded colidx capacity (pad-to-8 + prologue slack)
#define LSTR 136                 // LDS A-tile row stride (u16)

typedef __bf16 bf16x8 __attribute__((ext_vector_type(8)));
typedef float floatx4 __attribute__((ext_vector_type(4)));
typedef unsigned short u16;
typedef unsigned int u32;

__device__ __forceinline__ float b2f(u32 u) {
    union { u32 i; float f; } v; v.i = u << 16; return v.f;
}
__device__ __forceinline__ float b2f_hi(u32 u) {
    union { u32 i; float f; } v; v.i = u & 0xffff0000u; return v.f;
}
__device__ __forceinline__ u16 f2b(float f) {
    union { float f; u32 i; } v; v.f = f;
    u32 r = v.i + 0x7fffu + ((v.i >> 16) & 1u);   // RNE
    return (u16)(r >> 16);
}
__device__ __forceinline__ u32 pack2(float a, float b) {
    return (u32)f2b(a) | ((u32)f2b(b) << 16);
}

// ---------------- setup: zero counts/emb, fill padded colidx with dummy Nn, zero pad rows ----------------
__global__ __launch_bounds__(256) void k_setup(int* counts, float* emb, int* pcol,
                                               u16* xb, u16* hA, u16* hB, float* dinv) {
    int i = blockIdx.x * 256 + threadIdx.x;
    if (i < Nn) counts[i] = 0;
    if (i < Gg * Hh) emb[i] = 0.f;
    if (i * 4 < PCAP) {
        int4 v = { Nn, Nn, Nn, Nn };
        *(int4*)(pcol + i * 4) = v;
    }
    if (blockIdx.x == 0) {
        int t = threadIdx.x;
        uint4 z = { 0, 0, 0, 0 };
        if (t < 16)              *(uint4*)(xb + (size_t)Nn * 128 + t * 8) = z;
        else if (t < 32)         *(uint4*)(hA + (size_t)Nn * 128 + (t - 16) * 8) = z;
        else if (t < 48)         *(uint4*)(hB + (size_t)Nn * 128 + (t - 32) * 8) = z;
        else if (t == 48)        dinv[Nn] = 0.f;
    }
}

// ---------------- degree count (edge atomics over 40k counters — low contention) ----------------
// NOTE (R12 post-mortem): never fold per-graph counting in here — 40k atomics onto 32 addresses
// serialize ~1250-deep (~260 µs). gcnt is derived by binary search in k_final.
__global__ __launch_bounds__(256) void k_count(const int* __restrict__ dst, int* __restrict__ counts) {
    int i = blockIdx.x * 256 + threadIdx.x;
    if (i < Ee) atomicAdd(&counts[dst[i]], 1);
}

// ---------------- 3-phase multi-block exclusive scan over pad-to-8 counts ----------------
__global__ __launch_bounds__(256) void k_scan1(const int* __restrict__ counts, int* __restrict__ bsum) {
    __shared__ int sm[256];
    int t = threadIdx.x;
    int i = blockIdx.x * 256 + t;
    sm[t] = (i < Nn) ? ((counts[i] + 7) & ~7) : 0;
    __syncthreads();
    for (int ofs = 128; ofs > 0; ofs >>= 1) {
        if (t < ofs) sm[t] += sm[t + ofs];
        __syncthreads();
    }
    if (t == 0) bsum[blockIdx.x] = sm[0];
}

__global__ __launch_bounds__(256) void k_scan2(const int* __restrict__ bsum, int* __restrict__ boff,
                                               int* __restrict__ row_ptr) {
    __shared__ int sm[256];
    int t = threadIdx.x;
    int v = (t < NB) ? bsum[t] : 0;
    sm[t] = v;
    __syncthreads();
    for (int ofs = 1; ofs < 256; ofs <<= 1) {
        int u = (t >= ofs) ? sm[t - ofs] : 0;
        __syncthreads();
        sm[t] += u;
        __syncthreads();
    }
    if (t < NB) boff[t] = sm[t] - v;
    if (t == 255) row_ptr[Nn] = sm[255];
}

// cursor may alias counts — each thread reads counts[i] before writing cursor[i].
__global__ __launch_bounds__(256) void k_scan3(const int* counts, const int* __restrict__ boff,
                                               int* row_ptr, int* cursor, float* dinv) {
    __shared__ int sm[256];
    int t = threadIdx.x;
    int i = blockIdx.x * 256 + t;
    int c = (i < Nn) ? counts[i] : 0;
    int pc = (c + 7) & ~7;
    sm[t] = pc;
    __syncthreads();
    for (int ofs = 1; ofs < 256; ofs <<= 1) {
        int u = (t >= ofs) ? sm[t - ofs] : 0;
        __syncthreads();
        sm[t] += u;
        __syncthreads();
    }
    if (i < Nn) {
        int excl = sm[t] - pc + boff[blockIdx.x];
        row_ptr[i] = excl;
        cursor[i] = excl;
        dinv[i] = rsqrtf((float)(c + 1));
    }
}

__global__ __launch_bounds__(256) void k_scatter(const int* __restrict__ src, const int* __restrict__ dst,
                                                 int* __restrict__ cursor, int* __restrict__ colidx) {
    int i = blockIdx.x * 256 + threadIdx.x;
    if (i < Ee) {
        int d = dst[i];
        int p = atomicAdd(&cursor[d], 1);
        if ((u32)p < (u32)PCAP) colidx[p] = src[i];
    }
}

// ---------------- fused cast (f32->bf16 rows) + weight pack (MFMA B-frag order) ----------------
__global__ __launch_bounds__(256) void k_castpack(const float* __restrict__ x, u16* __restrict__ xb,
                                                  const float* w0, const float* w1, const float* w2,
                                                  const float* w3, const float* w4, const float* w5,
                                                  const float* w6, u16* __restrict__ pwdst) {
    if (blockIdx.x < 448) {
        int idx = blockIdx.x * 256 + threadIdx.x;
        if (idx < 7 * 16384) {
            const float* ws[7] = { w0, w1, w2, w3, w4, w5, w6 };
            int mat = idx >> 14, r = idx & 16383;
            int j = r & 7, n = (r >> 3) & 15, q = (r >> 7) & 3, nt = (r >> 9) & 7, t = r >> 12;
            pwdst[idx] = f2b(ws[mat][(t * 32 + q * 8 + j) * 128 + nt * 16 + n]);
        }
    } else {
        int i = ((blockIdx.x - 448) * 256 + threadIdx.x) * 4;   // covers Nn*128 = 5.12M exactly
        float4 v = *(const float4*)(x + i);
        ushort4 o = { f2b(v.x), f2b(v.y), f2b(v.z), f2b(v.w) };
        *(ushort4*)(xb + i) = o;
    }
}

// ---------------- FUSED layer: high-MLP gather-agg (R11 structure) -> LDS -> MFMA GEMM [-> pooled epilogue] ----------------
// Phase A: 4 parallel 16-lane groups per wave (one node each), 8 gathers in flight per iteration.
// MLP is the controlling variable (R7-R13 evidence) — do NOT serialize nodes per wave (R12/R13 lost ~28 µs).
#define UNPACK_ADD(V)                                   \
    a0 += b2f((V).x);  a1 += b2f_hi((V).x);             \
    a2 += b2f((V).y);  a3 += b2f_hi((V).y);             \
    a4 += b2f((V).z);  a5 += b2f_hi((V).z);             \
    a6 += b2f((V).w);  a7 += b2f_hi((V).w);

#define UNPACK_FMA(V, d)                                      \
    a0 += (d) * b2f((V).x);  a1 += (d) * b2f_hi((V).x);       \
    a2 += (d) * b2f((V).y);  a3 += (d) * b2f_hi((V).y);       \
    a4 += (d) * b2f((V).z);  a5 += (d) * b2f_hi((V).z);       \
    a6 += (d) * b2f((V).w);  a7 += (d) * b2f_hi((V).w);

__global__ __launch_bounds__(256) void k_layer(const u16* __restrict__ hin,
                                               const u16* __restrict__ Bp_agg,
                                               const u16* __restrict__ Bp_self,
                                               const float* __restrict__ bias,
                                               u16* __restrict__ hout,
                                               const int* __restrict__ prow,
                                               const int* __restrict__ pcol,
                                               const float* __restrict__ dinv,
                                               const int* __restrict__ batch,
                                               float* __restrict__ emb,
                                               int gcn, int relu, int dopool) {
    __shared__ u16 Asm[16 * LSTR];
    __shared__ float Psm[16][132];   // +4 pad for pooled-epilogue writes
    int wave = threadIdx.x >> 6, lane = threadIdx.x & 63;
    int m0 = blockIdx.x * 16;

    // ---- phase A: aggregate this block's 16 nodes (4 per wave, 16 lanes each, 8-deep pipeline) ----
    {
        int g = lane >> 4, l = lane & 15;
        int nloc = wave * 4 + g;
        int node = m0 + nloc;
        int beg = prow[node], end = prow[node + 1];
        float a0 = 0.f, a1 = 0.f, a2 = 0.f, a3 = 0.f, a4 = 0.f, a5 = 0.f, a6 = 0.f, a7 = 0.f;
        const u16* base = hin + l * 8;
        int4 i0 = {Nn,Nn,Nn,Nn}, i1 = {Nn,Nn,Nn,Nn};
        if (beg < end) {
            i0 = *(const int4*)(pcol + beg);
            i1 = *(const int4*)(pcol + beg + 4);
        }
        if (gcn) {
            for (int e = beg; e < end; e += 8) {
                int en = (e + 8 < end) ? (e + 8) : beg;
                int4 j0 = *(const int4*)(pcol + en);
                int4 j1 = *(const int4*)(pcol + en + 4);
                float d0 = dinv[i0.x], d1 = dinv[i0.y], d2 = dinv[i0.z], d3 = dinv[i0.w];
                float d4 = dinv[i1.x], d5 = dinv[i1.y], d6 = dinv[i1.z], d7 = dinv[i1.w];
                uint4 v0 = *(const uint4*)(base + (size_t)i0.x * 128);
                uint4 v1 = *(const uint4*)(base + (size_t)i0.y * 128);
                uint4 v2 = *(const uint4*)(base + (size_t)i0.z * 128);
                uint4 v3 = *(const uint4*)(base + (size_t)i0.w * 128);
                uint4 v4 = *(const uint4*)(base + (size_t)i1.x * 128);
                uint4 v5 = *(const uint4*)(base + (size_t)i1.y * 128);
                uint4 v6 = *(const uint4*)(base + (size_t)i1.z * 128);
                uint4 v7 = *(const uint4*)(base + (size_t)i1.w * 128);
                UNPACK_FMA(v0, d0) UNPACK_FMA(v1, d1) UNPACK_FMA(v2, d2) UNPACK_FMA(v3, d3)
                UNPACK_FMA(v4, d4) UNPACK_FMA(v5, d5) UNPACK_FMA(v6, d6) UNPACK_FMA(v7, d7)
                i0 = j0; i1 = j1;
            }
            float di = dinv[node], d2n = di * di;
            uint4 us = *(const uint4*)(base + (size_t)node * 128);
            a0 = di * a0 + d2n * b2f(us.x);  a1 = di * a1 + d2n * b2f_hi(us.x);
            a2 = di * a2 + d2n * b2f(us.y);  a3 = di * a3 + d2n * b2f_hi(us.y);
            a4 = di * a4 + d2n * b2f(us.z);  a5 = di * a5 + d2n * b2f_hi(us.z);
            a6 = di * a6 + d2n * b2f(us.w);  a7 = di * a7 + d2n * b2f_hi(us.w);
        } else {
            for (int e = beg; e < end; e += 8) {
                int en = (e + 8 < end) ? (e + 8) : beg;
                int4 j0 = *(const int4*)(pcol + en);
                int4 j1 = *(const int4*)(pcol + en + 4);
                uint4 v0 = *(const uint4*)(base + (size_t)i0.x * 128);
                uint4 v1 = *(const uint4*)(base + (size_t)i0.y * 128);
                uint4 v2 = *(const uint4*)(base + (size_t)i0.z * 128);
                uint4 v3 = *(const uint4*)(base + (size_t)i0.w * 128);
                uint4 v4 = *(const uint4*)(base + (size_t)i1.x * 128);
                uint4 v5 = *(const uint4*)(base + (size_t)i1.y * 128);
                uint4 v6 = *(const uint4*)(base + (size_t)i1.z * 128);
                uint4 v7 = *(const uint4*)(base + (size_t)i1.w * 128);
                UNPACK_ADD(v0) UNPACK_ADD(v1) UNPACK_ADD(v2) UNPACK_ADD(v3)
                UNPACK_ADD(v4) UNPACK_ADD(v5) UNPACK_ADD(v6) UNPACK_ADD(v7)
                i0 = j0; i1 = j1;
            }
        }
        uint4 o = { pack2(a0, a1), pack2(a2, a3), pack2(a4, a5), pack2(a6, a7) };
        *(uint4*)&Asm[nloc * LSTR + l * 8] = o;
    }
    __syncthreads();

    // ---- phase B: 16-row GEMM; wave handles cols [wave*32, wave*32+32) ----
    {
        int n = lane & 15, q = lane >> 4;
        floatx4 acc0 = (floatx4){0.f, 0.f, 0.f, 0.f};
        floatx4 acc1 = (floatx4){0.f, 0.f, 0.f, 0.f};
        int nt0 = wave * 2, nt1 = wave * 2 + 1;
#pragma unroll
        for (int t = 0; t < 4; t++) {
            bf16x8 a = *(const bf16x8*)&Asm[n * LSTR + q * 8 + t * 32];
            const u16* bp = Bp_agg + t * 4096 + q * 128 + n * 8;
            bf16x8 b0 = *(const bf16x8*)(bp + nt0 * 512);
            bf16x8 b1 = *(const bf16x8*)(bp + nt1 * 512);
            acc0 = __builtin_amdgcn_mfma_f32_16x16x32_bf16(a, b0, acc0, 0, 0, 0);
            acc1 = __builtin_amdgcn_mfma_f32_16x16x32_bf16(a, b1, acc1, 0, 0, 0);
        }
        if (!gcn) {
            const u16* arow = hin + (size_t)(m0 + n) * 128 + q * 8;
#pragma unroll
            for (int t = 0; t < 4; t++) {
                bf16x8 a = *(const bf16x8*)(arow + t * 32);
                const u16* bp = Bp_self + t * 4096 + q * 128 + n * 8;
                bf16x8 b0 = *(const bf16x8*)(bp + nt0 * 512);
                bf16x8 b1 = *(const bf16x8*)(bp + nt1 * 512);
                acc0 = __builtin_amdgcn_mfma_f32_16x16x32_bf16(a, b0, acc0, 0, 0, 0);
                acc1 = __builtin_amdgcn_mfma_f32_16x16x32_bf16(a, b1, acc1, 0, 0, 0);
            }
        }
        // D: row = q*4 + r, col = nt*16 + n
        if (dopool) {
#pragma unroll
            for (int j = 0; j < 2; j++) {
                int col = (wave * 2 + j) * 16 + n;
                float bv = bias[col];
                floatx4 ac = j ? acc1 : acc0;
#pragma unroll
                for (int r = 0; r < 4; r++)
                    Psm[q * 4 + r][col] = ac[r] + bv;
            }
            __syncthreads();
            if (threadIdx.x < 128) {
                int col = threadIdx.x;
                int g0 = batch[m0], g1 = batch[m0 + 15];
                for (int g = g0; g <= g1; ++g) {
                    float s = 0.f;
#pragma unroll
                    for (int i = 0; i < 16; ++i)
                        if (batch[m0 + i] == g) s += Psm[i][col];
                    atomicAdd(&emb[g * 128 + col], s);
                }
            }
        } else {
#pragma unroll
            for (int j = 0; j < 2; j++) {
                int col = (wave * 2 + j) * 16 + n;
                float bv = bias[col];
                floatx4 ac = j ? acc1 : acc0;
#pragma unroll
                for (int r = 0; r < 4; r++) {
                    float v = ac[r] + bv;
                    if (relu) v = fmaxf(v, 0.f);
                    hout[(size_t)(m0 + q * 4 + r) * 128 + col] = f2b(v);
                }
            }
        }
    }
}

// ---------------- final: gcnt via binary search (batch sorted) + embedding + logits (f32 out) ----------------
__global__ __launch_bounds__(256) void k_final(const float* __restrict__ emb, const int* __restrict__ batch,
                                               const float* __restrict__ lw, const float* __restrict__ lb,
                                               float* __restrict__ out) {
    __shared__ float cnt[Gg];
    int t = threadIdx.x;
    if (t < Gg) {
        int lo = 0, hi = Nn;
        while (lo < hi) { int m = (lo + hi) >> 1; if (batch[m] < t) lo = m + 1; else hi = m; }
        int lb0 = lo;
        lo = 0; hi = Nn;
        int tg = t + 1;
        while (lo < hi) { int m = (lo + hi) >> 1; if (batch[m] < tg) lo = m + 1; else hi = m; }
        cnt[t] = fmaxf((float)(lo - lb0), 1.f);
    }
    __syncthreads();
    for (int i = t; i < Gg * Hh; i += 256) {
        int g = i >> 7;
        out[Gg * Cc + i] = emb[i] / cnt[g];
    }
    if (t < Gg * Cc) {
        int g = t / Cc, c = t % Cc;
        float cn = cnt[g];
        float s = lb[c];
        for (int f = 0; f < Hh; f++)
            s += (emb[g * 128 + f] / cn) * lw[f * Cc + c];
        out[t] = s;
    }
}

extern "C" void kernel_launch(void* const* d_in, const int* in_sizes, int n_in,
                              void* d_out, int out_size, void* d_ws, size_t ws_size,
                              hipStream_t stream) {
    const float* x       = (const float*)d_in[0];
    const int*   ei      = (const int*)d_in[1];
    const int*   batch   = (const int*)d_in[2];
    const float* w1_root = (const float*)d_in[3];
    const float* w1_rel  = (const float*)d_in[4];
    const float* b1      = (const float*)d_in[5];
    const float* w2_root = (const float*)d_in[6];
    const float* w2_rel  = (const float*)d_in[7];
    const float* b2      = (const float*)d_in[8];
    const float* w3      = (const float*)d_in[9];
    const float* b3      = (const float*)d_in[10];
    const float* w4      = (const float*)d_in[11];
    const float* b4      = (const float*)d_in[12];
    const float* w5      = (const float*)d_in[13];
    const float* b5      = (const float*)d_in[14];
    const float* lw      = (const float*)d_in[15];
    const float* lb      = (const float*)d_in[16];
    const int* srcp = ei;
    const int* dstp = ei + Ee;
    float* out = (float*)d_out;

    char* w = (char*)d_ws;
    size_t off = 0;
    auto alloc = [&](size_t bytes) { size_t r = off; off += (bytes + 255) & ~(size_t)255; return r; };
    int*   counts  = (int*)(w + alloc(Nn * 4));              // doubles as scatter cursor
    int*   row_ptr = (int*)(w + alloc((Nn + 1) * 4));
    int*   colidx  = (int*)(w + alloc((size_t)PCAP * 4));
    float* dinv    = (float*)(w + alloc((Nn + 1) * 4));      // +1: dinv[Nn]=0 for pad edges
    float* emb     = (float*)(w + alloc(Gg * Hh * 4));
    int*   bsum    = (int*)(w + alloc(NB * 4));
    int*   boff    = (int*)(w + alloc(256 * 4));
    u16*   pw      = (u16*)(w + alloc(7 * 16384 * 2));
    u16*   xb      = (u16*)(w + alloc((size_t)(Nn + 1) * Hh * 2));  // +1 zero row
    u16*   hA      = (u16*)(w + alloc((size_t)(Nn + 1) * Hh * 2));
    u16*   hB      = (u16*)(w + alloc((size_t)(Nn + 1) * Hh * 2));
    (void)ws_size;

    u16* pw1r = pw + 0 * 16384;
    u16* pw1l = pw + 1 * 16384;
    u16* pw2r = pw + 2 * 16384;
    u16* pw2l = pw + 3 * 16384;
    u16* pw3  = pw + 4 * 16384;
    u16* pw4  = pw + 5 * 16384;
    u16* pw5  = pw + 6 * 16384;
    const u16* nil = (const u16*)nullptr;

    // CSR build (pad-to-8) + cast/pack
    hipLaunchKernelGGL(k_setup, dim3((PCAP / 4 + 255) / 256), dim3(256), 0, stream,
                       counts, emb, colidx, xb, hA, hB, dinv);
    hipLaunchKernelGGL(k_count, dim3((Ee + 255) / 256), dim3(256), 0, stream, dstp, counts);
    hipLaunchKernelGGL(k_scan1, dim3(NB), dim3(256), 0, stream, counts, bsum);
    hipLaunchKernelGGL(k_scan2, dim3(1), dim3(256), 0, stream, bsum, boff, row_ptr);
    hipLaunchKernelGGL(k_scan3, dim3(NB), dim3(256), 0, stream, counts, boff, row_ptr, counts, dinv);
    hipLaunchKernelGGL(k_scatter, dim3((Ee + 255) / 256), dim3(256), 0, stream, srcp, dstp, counts, colidx);
    hipLaunchKernelGGL(k_castpack, dim3(448 + Nn * Hh / 1024), dim3(256), 0, stream,
                       x, xb, w1_root, w1_rel, w2_root, w2_rel, w3, w4, w5, pw);

    // fused layers (block = 16 nodes, 2500 blocks)
    hipLaunchKernelGGL(k_layer, dim3(Nn / 16), dim3(256), 0, stream,
                       xb, pw1l, pw1r, b1, hA, row_ptr, colidx, dinv, batch, emb, 0, 1, 0);
    hipLaunchKernelGGL(k_layer, dim3(Nn / 16), dim3(256), 0, stream,
                       hA, pw2l, pw2r, b2, hB, row_ptr, colidx, dinv, batch, emb, 0, 1, 0);
    hipLaunchKernelGGL(k_layer, dim3(Nn / 16), dim3(256), 0, stream,
                       hB, pw3, nil, b3, hA, row_ptr, colidx, dinv, batch, emb, 1, 1, 0);
    hipLaunchKernelGGL(k_layer, dim3(Nn / 16), dim3(256), 0, stream,
                       hA, pw4, nil, b4, hB, row_ptr, colidx, dinv, batch, emb, 1, 1, 0);
    // L5 GCN, no relu, pooled epilogue (no hout write)
    hipLaunchKernelGGL(k_layer, dim3(Nn / 16), dim3(256), 0, stream,
                       hB, pw5, nil, b5, hA, row_ptr, colidx, dinv, batch, emb, 1, 0, 1);

    // final linear + embedding output (gcnt via binary search)
    hipLaunchKernelGGL(k_final, dim3(1), dim3(256), 0, stream, emb, batch, lw, lb, out);
}

// Round 15
// 313.712 us; speedup vs baseline: 1.8470x; 1.0181x over previous
//
#include <hip/hip_runtime.h>

#define Nn 40000
#define Ee 600000
#define Hh 128
#define Gg 32
#define Cc 6
#define NB 157                   // ceil(Nn/256) scan blocks
#define PCAP (Ee + 8 * Nn + 8)   // padded colidx capacity (pad-to-8 + slack)
#define LSTR 136                 // LDS A-tile row stride (u16)

typedef __bf16 bf16x8 __attribute__((ext_vector_type(8)));
typedef float floatx4 __attribute__((ext_vector_type(4)));
typedef unsigned short u16;
typedef unsigned int u32;

__device__ __forceinline__ float b2f(u32 u) {
    union { u32 i; float f; } v; v.i = u << 16; return v.f;
}
__device__ __forceinline__ float b2f_hi(u32 u) {
    union { u32 i; float f; } v; v.i = u & 0xffff0000u; return v.f;
}
__device__ __forceinline__ u16 f2b(float f) {
    union { float f; u32 i; } v; v.f = f;
    u32 r = v.i + 0x7fffu + ((v.i >> 16) & 1u);   // RNE
    return (u16)(r >> 16);
}
__device__ __forceinline__ u32 pack2(float a, float b) {
    return (u32)f2b(a) | ((u32)f2b(b) << 16);
}

// ---------------- setup + castpack merged: zero counts/emb/done, zero pad rows,
// pack 7 weight matrices into MFMA B-frag order, cast x -> bf16 rows ----------------
// grid = 448 pack blocks + 5000 cast blocks; init guards ride on the low block indices.
__global__ __launch_bounds__(256) void k_setup(int* counts, float* emb, int* done,
                                               u16* xb, u16* hA, u16* hB, float* dinv,
                                               const float* __restrict__ x,
                                               const float* w0, const float* w1, const float* w2,
                                               const float* w3, const float* w4, const float* w5,
                                               const float* w6, u16* __restrict__ pwdst) {
    int gid = blockIdx.x * 256 + threadIdx.x;
    if (gid < Nn) counts[gid] = 0;
    if (gid < Gg * Hh) emb[gid] = 0.f;
    if (gid == 0) *done = 0;
    if (blockIdx.x == 0) {
        int t = threadIdx.x;
        uint4 z = { 0, 0, 0, 0 };
        if (t < 16)              *(uint4*)(xb + (size_t)Nn * 128 + t * 8) = z;
        else if (t < 32)         *(uint4*)(hA + (size_t)Nn * 128 + (t - 16) * 8) = z;
        else if (t < 48)         *(uint4*)(hB + (size_t)Nn * 128 + (t - 32) * 8) = z;
        else if (t == 48)        dinv[Nn] = 0.f;
    }
    if (blockIdx.x < 448) {
        int idx = gid;
        if (idx < 7 * 16384) {
            const float* ws[7] = { w0, w1, w2, w3, w4, w5, w6 };
            int mat = idx >> 14, r = idx & 16383;
            int j = r & 7, n = (r >> 3) & 15, q = (r >> 7) & 3, nt = (r >> 9) & 7, t = r >> 12;
            pwdst[idx] = f2b(ws[mat][(t * 32 + q * 8 + j) * 128 + nt * 16 + n]);
        }
    } else {
        int i = ((blockIdx.x - 448) * 256 + threadIdx.x) * 4;   // covers Nn*128 = 5.12M exactly
        float4 v = *(const float4*)(x + i);
        ushort4 o = { f2b(v.x), f2b(v.y), f2b(v.z), f2b(v.w) };
        *(ushort4*)(xb + i) = o;
    }
}

// ---------------- degree count (edge atomics over 40k counters — low contention) ----------------
// NOTE (R12): never count per-graph here — 40k atomics on 32 addrs cost ~260 µs. gcnt via bsearch in k_final.
__global__ __launch_bounds__(256) void k_count(const int* __restrict__ dst, int* __restrict__ counts) {
    int i = blockIdx.x * 256 + threadIdx.x;
    if (i < Ee) atomicAdd(&counts[dst[i]], 1);
}

// ---------------- scan phase 1+2 merged (last-finished-block does the 157-sum scan) ----------------
__global__ __launch_bounds__(256) void k_scan12(const int* __restrict__ counts, int* __restrict__ bsum,
                                                int* __restrict__ boff, int* __restrict__ row_ptr,
                                                int* __restrict__ done) {
    __shared__ int sm[256];
    __shared__ int lastFlag;
    int t = threadIdx.x;
    int i = blockIdx.x * 256 + t;
    sm[t] = (i < Nn) ? ((counts[i] + 7) & ~7) : 0;
    __syncthreads();
    for (int ofs = 128; ofs > 0; ofs >>= 1) {
        if (t < ofs) sm[t] += sm[t + ofs];
        __syncthreads();
    }
    if (t == 0) {
        bsum[blockIdx.x] = sm[0];
        __threadfence();
        int prev = atomicAdd(done, 1);
        lastFlag = (prev == NB - 1);
    }
    __syncthreads();
    if (!lastFlag) return;
    __threadfence();   // acquire: all blocks' bsum writes visible
    int v = (t < NB) ? bsum[t] : 0;
    sm[t] = v;
    __syncthreads();
    for (int ofs = 1; ofs < 256; ofs <<= 1) {
        int u = (t >= ofs) ? sm[t - ofs] : 0;
        __syncthreads();
        sm[t] += u;
        __syncthreads();
    }
    if (t < NB) boff[t] = sm[t] - v;
    if (t == 255) row_ptr[Nn] = sm[255];
}

// ---------------- scan3: apply offsets, write row_ptr/cursor/dinv, and write pad colidx entries ----------------
// cursor may alias counts — counts[i] read before cursor[i] write.
__global__ __launch_bounds__(256) void k_scan3(const int* counts, const int* __restrict__ boff,
                                               int* row_ptr, int* cursor, float* dinv,
                                               int* __restrict__ colidx) {
    __shared__ int sm[256];
    int t = threadIdx.x;
    int i = blockIdx.x * 256 + t;
    int c = (i < Nn) ? counts[i] : 0;
    int pc = (c + 7) & ~7;
    sm[t] = pc;
    __syncthreads();
    for (int ofs = 1; ofs < 256; ofs <<= 1) {
        int u = (t >= ofs) ? sm[t - ofs] : 0;
        __syncthreads();
        sm[t] += u;
        __syncthreads();
    }
    if (i < Nn) {
        int excl = sm[t] - pc + boff[blockIdx.x];
        row_ptr[i] = excl;
        cursor[i] = excl;
        dinv[i] = rsqrtf((float)(c + 1));
        for (int p = excl + c; p < excl + pc; ++p) colidx[p] = Nn;   // pads -> zero row
    }
}

__global__ __launch_bounds__(256) void k_scatter(const int* __restrict__ src, const int* __restrict__ dst,
                                                 int* __restrict__ cursor, int* __restrict__ colidx) {
    int i = blockIdx.x * 256 + threadIdx.x;
    if (i < Ee) {
        int d = dst[i];
        int p = atomicAdd(&cursor[d], 1);
        if ((u32)p < (u32)PCAP) colidx[p] = src[i];
    }
}

// ---------------- FUSED layer: high-MLP gather-agg (R11 structure) -> LDS -> MFMA GEMM [-> pooled epilogue] ----------------
// Phase A: 4 parallel 16-lane groups per wave (one node each), 8 gathers in flight.
// MLP is the controlling variable (R7-R13) — do NOT serialize nodes per wave (R12/R13 lost ~28 µs).
#define UNPACK_ADD(V)                                   \
    a0 += b2f((V).x);  a1 += b2f_hi((V).x);             \
    a2 += b2f((V).y);  a3 += b2f_hi((V).y);             \
    a4 += b2f((V).z);  a5 += b2f_hi((V).z);             \
    a6 += b2f((V).w);  a7 += b2f_hi((V).w);

#define UNPACK_FMA(V, d)                                      \
    a0 += (d) * b2f((V).x);  a1 += (d) * b2f_hi((V).x);       \
    a2 += (d) * b2f((V).y);  a3 += (d) * b2f_hi((V).y);       \
    a4 += (d) * b2f((V).z);  a5 += (d) * b2f_hi((V).z);       \
    a6 += (d) * b2f((V).w);  a7 += (d) * b2f_hi((V).w);

__global__ __launch_bounds__(256) void k_layer(const u16* __restrict__ hin,
                                               const u16* __restrict__ Bp_agg,
                                               const u16* __restrict__ Bp_self,
                                               const float* __restrict__ bias,
                                               u16* __restrict__ hout,
                                               const int* __restrict__ prow,
                                               const int* __restrict__ pcol,
                                               const float* __restrict__ dinv,
                                               const int* __restrict__ batch,
                                               float* __restrict__ emb,
                                               int gcn, int relu, int dopool) {
    __shared__ u16 Asm[16 * LSTR];
    __shared__ float Psm[16][132];
    int wave = threadIdx.x >> 6, lane = threadIdx.x & 63;
    int m0 = blockIdx.x * 16;

    // ---- phase A ----
    {
        int g = lane >> 4, l = lane & 15;
        int nloc = wave * 4 + g;
        int node = m0 + nloc;
        int beg = prow[node], end = prow[node + 1];
        float a0 = 0.f, a1 = 0.f, a2 = 0.f, a3 = 0.f, a4 = 0.f, a5 = 0.f, a6 = 0.f, a7 = 0.f;
        const u16* base = hin + l * 8;
        int4 i0 = {Nn,Nn,Nn,Nn}, i1 = {Nn,Nn,Nn,Nn};
        if (beg < end) {
            i0 = *(const int4*)(pcol + beg);
            i1 = *(const int4*)(pcol + beg + 4);
        }
        if (gcn) {
            for (int e = beg; e < end; e += 8) {
                int en = (e + 8 < end) ? (e + 8) : beg;
                int4 j0 = *(const int4*)(pcol + en);
                int4 j1 = *(const int4*)(pcol + en + 4);
                float d0 = dinv[i0.x], d1 = dinv[i0.y], d2 = dinv[i0.z], d3 = dinv[i0.w];
                float d4 = dinv[i1.x], d5 = dinv[i1.y], d6 = dinv[i1.z], d7 = dinv[i1.w];
                uint4 v0 = *(const uint4*)(base + (size_t)i0.x * 128);
                uint4 v1 = *(const uint4*)(base + (size_t)i0.y * 128);
                uint4 v2 = *(const uint4*)(base + (size_t)i0.z * 128);
                uint4 v3 = *(const uint4*)(base + (size_t)i0.w * 128);
                uint4 v4 = *(const uint4*)(base + (size_t)i1.x * 128);
                uint4 v5 = *(const uint4*)(base + (size_t)i1.y * 128);
                uint4 v6 = *(const uint4*)(base + (size_t)i1.z * 128);
                uint4 v7 = *(const uint4*)(base + (size_t)i1.w * 128);
                UNPACK_FMA(v0, d0) UNPACK_FMA(v1, d1) UNPACK_FMA(v2, d2) UNPACK_FMA(v3, d3)
                UNPACK_FMA(v4, d4) UNPACK_FMA(v5, d5) UNPACK_FMA(v6, d6) UNPACK_FMA(v7, d7)
                i0 = j0; i1 = j1;
            }
            float di = dinv[node], d2n = di * di;
            uint4 us = *(const uint4*)(base + (size_t)node * 128);
            a0 = di * a0 + d2n * b2f(us.x);  a1 = di * a1 + d2n * b2f_hi(us.x);
            a2 = di * a2 + d2n * b2f(us.y);  a3 = di * a3 + d2n * b2f_hi(us.y);
            a4 = di * a4 + d2n * b2f(us.z);  a5 = di * a5 + d2n * b2f_hi(us.z);
            a6 = di * a6 + d2n * b2f(us.w);  a7 = di * a7 + d2n * b2f_hi(us.w);
        } else {
            for (int e = beg; e < end; e += 8) {
                int en = (e + 8 < end) ? (e + 8) : beg;
                int4 j0 = *(const int4*)(pcol + en);
                int4 j1 = *(const int4*)(pcol + en + 4);
                uint4 v0 = *(const uint4*)(base + (size_t)i0.x * 128);
                uint4 v1 = *(const uint4*)(base + (size_t)i0.y * 128);
                uint4 v2 = *(const uint4*)(base + (size_t)i0.z * 128);
                uint4 v3 = *(const uint4*)(base + (size_t)i0.w * 128);
                uint4 v4 = *(const uint4*)(base + (size_t)i1.x * 128);
                uint4 v5 = *(const uint4*)(base + (size_t)i1.y * 128);
                uint4 v6 = *(const uint4*)(base + (size_t)i1.z * 128);
                uint4 v7 = *(const uint4*)(base + (size_t)i1.w * 128);
                UNPACK_ADD(v0) UNPACK_ADD(v1) UNPACK_ADD(v2) UNPACK_ADD(v3)
                UNPACK_ADD(v4) UNPACK_ADD(v5) UNPACK_ADD(v6) UNPACK_ADD(v7)
                i0 = j0; i1 = j1;
            }
        }
        uint4 o = { pack2(a0, a1), pack2(a2, a3), pack2(a4, a5), pack2(a6, a7) };
        *(uint4*)&Asm[nloc * LSTR + l * 8] = o;
    }
    __syncthreads();

    // ---- phase B: 16-row GEMM; wave handles cols [wave*32, wave*32+32) ----
    {
        int n = lane & 15, q = lane >> 4;
        floatx4 acc0 = (floatx4){0.f, 0.f, 0.f, 0.f};
        floatx4 acc1 = (floatx4){0.f, 0.f, 0.f, 0.f};
        int nt0 = wave * 2, nt1 = wave * 2 + 1;
#pragma unroll
        for (int t = 0; t < 4; t++) {
            bf16x8 a = *(const bf16x8*)&Asm[n * LSTR + q * 8 + t * 32];
            const u16* bp = Bp_agg + t * 4096 + q * 128 + n * 8;
            bf16x8 b0 = *(const bf16x8*)(bp + nt0 * 512);
            bf16x8 b1 = *(const bf16x8*)(bp + nt1 * 512);
            acc0 = __builtin_amdgcn_mfma_f32_16x16x32_bf16(a, b0, acc0, 0, 0, 0);
            acc1 = __builtin_amdgcn_mfma_f32_16x16x32_bf16(a, b1, acc1, 0, 0, 0);
        }
        if (!gcn) {
            const u16* arow = hin + (size_t)(m0 + n) * 128 + q * 8;
#pragma unroll
            for (int t = 0; t < 4; t++) {
                bf16x8 a = *(const bf16x8*)(arow + t * 32);
                const u16* bp = Bp_self + t * 4096 + q * 128 + n * 8;
                bf16x8 b0 = *(const bf16x8*)(bp + nt0 * 512);
                bf16x8 b1 = *(const bf16x8*)(bp + nt1 * 512);
                acc0 = __builtin_amdgcn_mfma_f32_16x16x32_bf16(a, b0, acc0, 0, 0, 0);
                acc1 = __builtin_amdgcn_mfma_f32_16x16x32_bf16(a, b1, acc1, 0, 0, 0);
            }
        }
        if (dopool) {
#pragma unroll
            for (int j = 0; j < 2; j++) {
                int col = (wave * 2 + j) * 16 + n;
                float bv = bias[col];
                floatx4 ac = j ? acc1 : acc0;
#pragma unroll
                for (int r = 0; r < 4; r++)
                    Psm[q * 4 + r][col] = ac[r] + bv;
            }
            __syncthreads();
            if (threadIdx.x < 128) {
                int col = threadIdx.x;
                int g0 = batch[m0], g1 = batch[m0 + 15];
                for (int g = g0; g <= g1; ++g) {
                    float s = 0.f;
#pragma unroll
                    for (int i = 0; i < 16; ++i)
                        if (batch[m0 + i] == g) s += Psm[i][col];
                    atomicAdd(&emb[g * 128 + col], s);
                }
            }
        } else {
#pragma unroll
            for (int j = 0; j < 2; j++) {
                int col = (wave * 2 + j) * 16 + n;
                float bv = bias[col];
                floatx4 ac = j ? acc1 : acc0;
#pragma unroll
                for (int r = 0; r < 4; r++) {
                    float v = ac[r] + bv;
                    if (relu) v = fmaxf(v, 0.f);
                    hout[(size_t)(m0 + q * 4 + r) * 128 + col] = f2b(v);
                }
            }
        }
    }
}

// ---------------- final: gcnt via binary search (batch sorted) + embedding + logits (f32 out) ----------------
__global__ __launch_bounds__(256) void k_final(const float* __restrict__ emb, const int* __restrict__ batch,
                                               const float* __restrict__ lw, const float* __restrict__ lb,
                                               float* __restrict__ out) {
    __shared__ float cnt[Gg];
    int t = threadIdx.x;
    if (t < Gg) {
        int lo = 0, hi = Nn;
        while (lo < hi) { int m = (lo + hi) >> 1; if (batch[m] < t) lo = m + 1; else hi = m; }
        int lb0 = lo;
        lo = 0; hi = Nn;
        int tg = t + 1;
        while (lo < hi) { int m = (lo + hi) >> 1; if (batch[m] < tg) lo = m + 1; else hi = m; }
        cnt[t] = fmaxf((float)(lo - lb0), 1.f);
    }
    __syncthreads();
    for (int i = t; i < Gg * Hh; i += 256) {
        int g = i >> 7;
        out[Gg * Cc + i] = emb[i] / cnt[g];
    }
    if (t < Gg * Cc) {
        int g = t / Cc, c = t % Cc;
        float cn = cnt[g];
        float s = lb[c];
        for (int f = 0; f < Hh; f++)
            s += (emb[g * 128 + f] / cn) * lw[f * Cc + c];
        out[t] = s;
    }
}

extern "C" void kernel_launch(void* const* d_in, const int* in_sizes, int n_in,
                              void* d_out, int out_size, void* d_ws, size_t ws_size,
                              hipStream_t stream) {
    const float* x       = (const float*)d_in[0];
    const int*   ei      = (const int*)d_in[1];
    const int*   batch   = (const int*)d_in[2];
    const float* w1_root = (const float*)d_in[3];
    const float* w1_rel  = (const float*)d_in[4];
    const float* b1      = (const float*)d_in[5];
    const float* w2_root = (const float*)d_in[6];
    const float* w2_rel  = (const float*)d_in[7];
    const float* b2      = (const float*)d_in[8];
    const float* w3      = (const float*)d_in[9];
    const float* b3      = (const float*)d_in[10];
    const float* w4      = (const float*)d_in[11];
    const float* b4      = (const float*)d_in[12];
    const float* w5      = (const float*)d_in[13];
    const float* b5      = (const float*)d_in[14];
    const float* lw      = (const float*)d_in[15];
    const float* lb      = (const float*)d_in[16];
    const int* srcp = ei;
    const int* dstp = ei + Ee;
    float* out = (float*)d_out;

    char* w = (char*)d_ws;
    size_t off = 0;
    auto alloc = [&](size_t bytes) { size_t r = off; off += (bytes + 255) & ~(size_t)255; return r; };
    int*   counts  = (int*)(w + alloc(Nn * 4));              // doubles as scatter cursor
    int*   row_ptr = (int*)(w + alloc((Nn + 1) * 4));
    int*   colidx  = (int*)(w + alloc((size_t)PCAP * 4));
    float* dinv    = (float*)(w + alloc((Nn + 1) * 4));      // dinv[Nn]=0 for pad edges
    float* emb     = (float*)(w + alloc(Gg * Hh * 4));
    int*   bsum    = (int*)(w + alloc(NB * 4));
    int*   boff    = (int*)(w + alloc(256 * 4));
    int*   done    = (int*)(w + alloc(256));
    u16*   pw      = (u16*)(w + alloc(7 * 16384 * 2));
    u16*   xb      = (u16*)(w + alloc((size_t)(Nn + 1) * Hh * 2));  // +1 zero row
    u16*   hA      = (u16*)(w + alloc((size_t)(Nn + 1) * Hh * 2));
    u16*   hB      = (u16*)(w + alloc((size_t)(Nn + 1) * Hh * 2));
    (void)ws_size;

    u16* pw1r = pw + 0 * 16384;
    u16* pw1l = pw + 1 * 16384;
    u16* pw2r = pw + 2 * 16384;
    u16* pw2l = pw + 3 * 16384;
    u16* pw3  = pw + 4 * 16384;
    u16* pw4  = pw + 5 * 16384;
    u16* pw5  = pw + 6 * 16384;
    const u16* nil = (const u16*)nullptr;

    // preprocessing: 5 launches (was 7)
    hipLaunchKernelGGL(k_setup, dim3(448 + Nn * Hh / 1024), dim3(256), 0, stream,
                       counts, emb, done, xb, hA, hB, dinv,
                       x, w1_root, w1_rel, w2_root, w2_rel, w3, w4, w5, pw);
    hipLaunchKernelGGL(k_count, dim3((Ee + 255) / 256), dim3(256), 0, stream, dstp, counts);
    hipLaunchKernelGGL(k_scan12, dim3(NB), dim3(256), 0, stream, counts, bsum, boff, row_ptr, done);
    hipLaunchKernelGGL(k_scan3, dim3(NB), dim3(256), 0, stream, counts, boff, row_ptr, counts, dinv, colidx);
    hipLaunchKernelGGL(k_scatter, dim3((Ee + 255) / 256), dim3(256), 0, stream, srcp, dstp, counts, colidx);

    // fused layers (block = 16 nodes, 2500 blocks)
    hipLaunchKernelGGL(k_layer, dim3(Nn / 16), dim3(256), 0, stream,
                       xb, pw1l, pw1r, b1, hA, row_ptr, colidx, dinv, batch, emb, 0, 1, 0);
    hipLaunchKernelGGL(k_layer, dim3(Nn / 16), dim3(256), 0, stream,
                       hA, pw2l, pw2r, b2, hB, row_ptr, colidx, dinv, batch, emb, 0, 1, 0);
    hipLaunchKernelGGL(k_layer, dim3(Nn / 16), dim3(256), 0, stream,
                       hB, pw3, nil, b3, hA, row_ptr, colidx, dinv, batch, emb, 1, 1, 0);
    hipLaunchKernelGGL(k_layer, dim3(Nn / 16), dim3(256), 0, stream,
                       hA, pw4, nil, b4, hB, row_ptr, colidx, dinv, batch, emb, 1, 1, 0);
    hipLaunchKernelGGL(k_layer, dim3(Nn / 16), dim3(256), 0, stream,
                       hB, pw5, nil, b5, hA, row_ptr, colidx, dinv, batch, emb, 1, 0, 1);

    // final linear + embedding output (gcnt via binary search)
    hipLaunchKernelGGL(k_final, dim3(1), dim3(256), 0, stream, emb, batch, lw, lb, out);
}